// Round 9
// baseline (164.317 us; speedup 1.0000x reference)
//
#include <hip/hip_runtime.h>
#include <math.h>

#define B 2048
#define D 512
#define NC 32
#define G  32                    // top2 subtile-blocks per class
#define TS 516                   // LDS tile row stride in floats (512 + 4 pad)
#define TOTAL_BLOCKS (NC * (G + 1))

// ---------------------------------------------------------------------------
// Workspace: float centers[NC][D]; float blk_top[NC][G][2]; int cnt
// Single fused kernel; last-arriving block computes the final scalar.
// ---------------------------------------------------------------------------

// Build class-c member list (ascending order) in LDS via wave shuffle-scan.
__device__ inline int build_slist(const int* __restrict__ target, int c,
                                  short* slist, int* wtot) {
    const int t = threadIdx.x;
    const int wave = t >> 6;
    const int lane = t & 63;
    const int base = t * 8;
    int flags[8];
    int local = 0;
#pragma unroll
    for (int k = 0; k < 8; ++k) {
        flags[k] = (target[base + k] == c) ? 1 : 0;
        local += flags[k];
    }
    int incl = local;
#pragma unroll
    for (int off = 1; off < 64; off <<= 1) {
        const int v = __shfl_up(incl, off, 64);
        if (lane >= off) incl += v;
    }
    if (lane == 63) wtot[wave] = incl;
    __syncthreads();
    int wbase = 0;
    for (int w = 0; w < wave; ++w) wbase += wtot[w];
    const int n = wtot[0] + wtot[1] + wtot[2] + wtot[3];
    int pos = wbase + incl - local;
#pragma unroll
    for (int k = 0; k < 8; ++k) {
        if (flags[k]) slist[pos++] = (short)(base + k);
    }
    __syncthreads();
    return n;
}

__global__ void __launch_bounds__(256)
fused_kernel(const float* __restrict__ y,
             const int* __restrict__ target,
             float* __restrict__ centers,
             float* __restrict__ blk_top,
             int* __restrict__ cnt,
             float* __restrict__ out) {
    const int c = blockIdx.x;
    const int by = blockIdx.y;
    const int t = threadIdx.x;
    const int wave = t >> 6;
    const int lane = t & 63;

    __shared__ short slist[B];
    __shared__ int wtot[4];
    __shared__ float tile[16 * TS];
    __shared__ float partials[4][64];
    __shared__ float li_sh[NC];
    __shared__ float mn_sh[4];
    __shared__ int isLast;

    const int n = build_slist(target, c, slist, wtot);

    if (by == 0) {
        // -------- centers role: thread owns dims t, t+256; 8-way unrolled --
        float acc0 = 0.f, acc1 = 0.f;
        int m = 0;
        for (; m + 8 <= n; m += 8) {
#pragma unroll
            for (int k = 0; k < 8; ++k) {
                const float* r = y + (size_t)slist[m + k] * D;
                acc0 += r[t];
                acc1 += r[t + 256];
            }
        }
        for (; m < n; ++m) {
            const float* r = y + (size_t)slist[m] * D;
            acc0 += r[t];
            acc1 += r[t + 256];
        }
        const float den = fmaxf((float)n, 1.0f);
        centers[c * D + t]       = acc0 / den;
        centers[c * D + t + 256] = acc1 / den;
    } else {
        // -------- top2 role: 8x8 pair subtiles staged through LDS ----------
        const int nt = (n + 7) >> 3;
        const int nst = nt * (nt + 1) / 2;
        const int di = lane >> 3;
        const int dj = lane & 7;
        float t0 = -INFINITY, t1 = -INFINITY;  // wave-0 running top2

        for (int st = by - 1; st < nst; st += G) {
            int rem = st, ta = 0;
            while (rem >= nt - ta) { rem -= nt - ta; ++ta; }
            const int tb = ta + rem;

            // stage 16 rows (a: ta*8+r, b: tb*8+r) into LDS in one bulk round
            {
                const int r  = t >> 4;
                const int cg = (t & 15) * 32;
                const int gidx = (r < 8) ? (ta * 8 + r) : (tb * 8 + (r - 8));
                const int row  = (gidx < n) ? (int)slist[gidx] : 0;
                const float4* src = (const float4*)(y + (size_t)row * D + cg);
                float4* dst = (float4*)&tile[r * TS + cg];
#pragma unroll
                for (int q = 0; q < 8; ++q) dst[q] = src[q];
            }
            __syncthreads();

            // lane owns pair (di, dj); this wave covers dims [wave*128, +128)
            {
                const float* pa = &tile[di * TS]       + wave * 128;
                const float* pb = &tile[(8 + dj) * TS] + wave * 128;
                float s0 = 0.f, s1 = 0.f, s2 = 0.f, s3 = 0.f;
#pragma unroll
                for (int kk = 0; kk < 32; kk += 4) {
                    float4 a, b; float d;
                    a = ((const float4*)pa)[kk];     b = ((const float4*)pb)[kk];
                    d = a.x - b.x; s0 += d * d;  d = a.y - b.y; s0 += d * d;
                    d = a.z - b.z; s0 += d * d;  d = a.w - b.w; s0 += d * d;
                    a = ((const float4*)pa)[kk + 1]; b = ((const float4*)pb)[kk + 1];
                    d = a.x - b.x; s1 += d * d;  d = a.y - b.y; s1 += d * d;
                    d = a.z - b.z; s1 += d * d;  d = a.w - b.w; s1 += d * d;
                    a = ((const float4*)pa)[kk + 2]; b = ((const float4*)pb)[kk + 2];
                    d = a.x - b.x; s2 += d * d;  d = a.y - b.y; s2 += d * d;
                    d = a.z - b.z; s2 += d * d;  d = a.w - b.w; s2 += d * d;
                    a = ((const float4*)pa)[kk + 3]; b = ((const float4*)pb)[kk + 3];
                    d = a.x - b.x; s3 += d * d;  d = a.y - b.y; s3 += d * d;
                    d = a.z - b.z; s3 += d * d;  d = a.w - b.w; s3 += d * d;
                }
                partials[wave][lane] = (s0 + s1) + (s2 + s3);
            }
            __syncthreads();

            if (wave == 0) {
                const float ssd = partials[0][lane] + partials[1][lane] +
                                  partials[2][lane] + partials[3][lane];
                const int i = ta * 8 + di;
                const int j = tb * 8 + dj;
                const float dd = (i < j && j < n) ? sqrtf(ssd) : -INFINITY;
                if (dd > t0) { t1 = t0; t0 = dd; }
                else if (dd > t1) { t1 = dd; }
            }
            __syncthreads();
        }

        if (wave == 0) {
#pragma unroll
            for (int off = 32; off > 0; off >>= 1) {
                const float o0 = __shfl_xor(t0, off, 64);
                const float o1 = __shfl_xor(t1, off, 64);
                if (o0 > t0) { t1 = fmaxf(t0, o1); t0 = o0; }
                else         { t1 = fmaxf(t1, o0); }
            }
            if (lane == 0) {
                blk_top[(c * G + (by - 1)) * 2]     = t0;
                blk_top[(c * G + (by - 1)) * 2 + 1] = t1;
            }
        }
    }

    // ---- completion protocol: last-arriving block computes the scalar -----
    __syncthreads();
    __threadfence();
    if (t == 0) {
        const int old = atomicAdd(cnt, 1);
        isLast = (old == TOTAL_BLOCKS - 1) ? 1 : 0;
    }
    __syncthreads();
    if (!isLast) return;
    __threadfence();  // acquire all other blocks' results

    // tail A: per-class top-2 merge (wave w -> classes 8w..8w+7)
#pragma unroll
    for (int k = 0; k < 8; ++k) {
        const int cc = wave * 8 + k;
        float t0 = blk_top[cc * G * 2 + lane];   // 64 partials on 64 lanes
        float t1 = -INFINITY;
#pragma unroll
        for (int off = 32; off > 0; off >>= 1) {
            const float o0 = __shfl_xor(t0, off, 64);
            const float o1 = __shfl_xor(t1, off, 64);
            if (o0 > t0) { t1 = fmaxf(t0, o1); t0 = o0; }
            else         { t1 = fmaxf(t1, o0); }
        }
        if (lane == 0) li_sh[cc] = 2.0f / (t0 + t1);
    }

    // tail B: center-min, wave-per-pair (lanes split D), pairs independent
    float dmin = INFINITY;
    for (int slot = wave; slot < NC * NC; slot += 4) {
        const int i = slot >> 5;
        const int j = slot & 31;
        if (i >= j) continue;
        const float4* ca = (const float4*)(centers + i * D) + lane * 2;
        const float4* cb = (const float4*)(centers + j * D) + lane * 2;
        const float4 u0 = ca[0], u1 = ca[1];
        const float4 v0 = cb[0], v1 = cb[1];
        float d, ssd = 0.f;
        d = u0.x - v0.x; ssd += d * d;
        d = u0.y - v0.y; ssd += d * d;
        d = u0.z - v0.z; ssd += d * d;
        d = u0.w - v0.w; ssd += d * d;
        d = u1.x - v1.x; ssd += d * d;
        d = u1.y - v1.y; ssd += d * d;
        d = u1.z - v1.z; ssd += d * d;
        d = u1.w - v1.w; ssd += d * d;
#pragma unroll
        for (int off = 32; off > 0; off >>= 1) ssd += __shfl_xor(ssd, off, 64);
        dmin = fminf(dmin, sqrtf(ssd));
    }
    if (lane == 0) mn_sh[wave] = dmin;
    __syncthreads();

    // tail C: combine
    if (t == 0) {
        float m = INFINITY;
        for (int w = 0; w < 4; ++w) m = fminf(m, mn_sh[w]);
        float s = 0.f;
        for (int cc = 0; cc < NC; ++cc) s += li_sh[cc];
        out[0] = 1.0f * s + 0.5f * fmaxf(10.0f - m, 0.0f);
    }
}

extern "C" void kernel_launch(void* const* d_in, const int* in_sizes, int n_in,
                              void* d_out, int out_size, void* d_ws, size_t ws_size,
                              hipStream_t stream) {
    const float* y      = (const float*)d_in[0];
    const int*   target = (const int*)d_in[1];
    float*       out    = (float*)d_out;

    float* centers = (float*)d_ws;
    float* blk_top = centers + NC * D;
    int*   cnt     = (int*)(blk_top + NC * G * 2);

    hipMemsetAsync(cnt, 0, sizeof(int), stream);  // reset finish counter
    fused_kernel<<<dim3(NC, G + 1), 256, 0, stream>>>(y, target, centers,
                                                      blk_top, cnt, out);
}

// Round 10
// 124.528 us; speedup vs baseline: 1.3195x; 1.3195x over previous
//
#include <hip/hip_runtime.h>
#include <math.h>

#define B 2048
#define D 512
#define NC 32
#define G  32                    // top2 subtile-blocks per class
#define TS 516                   // LDS tile row stride in floats (512 + 4 pad)
#define TOTAL_BLOCKS (NC * (G + 1))
#define NPAIRS (NC * (NC - 1) / 2)   // 496 center pairs

// ---------------------------------------------------------------------------
// Workspace: float centers[NC][D]; float blk_top[NC][G][2]; int cnt
// Single fused kernel; last-arriving block computes the final scalar with
// LANE-parallel work (never one serial wave -- R9's mistake).
// ---------------------------------------------------------------------------

// Build class-c member list (ascending order) in LDS via wave shuffle-scan.
__device__ inline int build_slist(const int* __restrict__ target, int c,
                                  short* slist, int* wtot) {
    const int t = threadIdx.x;
    const int wave = t >> 6;
    const int lane = t & 63;
    const int base = t * 8;
    int flags[8];
    int local = 0;
#pragma unroll
    for (int k = 0; k < 8; ++k) {
        flags[k] = (target[base + k] == c) ? 1 : 0;
        local += flags[k];
    }
    int incl = local;
#pragma unroll
    for (int off = 1; off < 64; off <<= 1) {
        const int v = __shfl_up(incl, off, 64);
        if (lane >= off) incl += v;
    }
    if (lane == 63) wtot[wave] = incl;
    __syncthreads();
    int wbase = 0;
    for (int w = 0; w < wave; ++w) wbase += wtot[w];
    const int n = wtot[0] + wtot[1] + wtot[2] + wtot[3];
    int pos = wbase + incl - local;
#pragma unroll
    for (int k = 0; k < 8; ++k) {
        if (flags[k]) slist[pos++] = (short)(base + k);
    }
    __syncthreads();
    return n;
}

__global__ void __launch_bounds__(256)
fused_kernel(const float* __restrict__ y,
             const int* __restrict__ target,
             float* __restrict__ centers,
             float* __restrict__ blk_top,
             int* __restrict__ cnt,
             float* __restrict__ out) {
    const int c = blockIdx.x;
    const int by = blockIdx.y;
    const int t = threadIdx.x;
    const int wave = t >> 6;
    const int lane = t & 63;

    __shared__ short slist[B];
    __shared__ int wtot[4];
    __shared__ float tile[16 * TS];
    __shared__ float partials[4][64];
    __shared__ float li_sh[NC];
    __shared__ float mn_sh[4];
    __shared__ int isLast;

    const int n = build_slist(target, c, slist, wtot);

    if (by == 0) {
        // -------- centers role: thread owns dims t, t+256; 8-way unrolled --
        float acc0 = 0.f, acc1 = 0.f;
        int m = 0;
        for (; m + 8 <= n; m += 8) {
#pragma unroll
            for (int k = 0; k < 8; ++k) {
                const float* r = y + (size_t)slist[m + k] * D;
                acc0 += r[t];
                acc1 += r[t + 256];
            }
        }
        for (; m < n; ++m) {
            const float* r = y + (size_t)slist[m] * D;
            acc0 += r[t];
            acc1 += r[t + 256];
        }
        const float den = fmaxf((float)n, 1.0f);
        centers[c * D + t]       = acc0 / den;
        centers[c * D + t + 256] = acc1 / den;
    } else {
        // -------- top2 role: 8x8 pair subtiles staged through LDS ----------
        const int nt = (n + 7) >> 3;
        const int nst = nt * (nt + 1) / 2;
        const int di = lane >> 3;
        const int dj = lane & 7;
        float t0 = -INFINITY, t1 = -INFINITY;  // wave-0 running top2

        for (int st = by - 1; st < nst; st += G) {
            int rem = st, ta = 0;
            while (rem >= nt - ta) { rem -= nt - ta; ++ta; }
            const int tb = ta + rem;

            // stage 16 rows into LDS; column-interleaved so the 16 lanes of a
            // row hit 16 distinct bank groups (conflict-free ds_write_b128)
            {
                const int r  = t >> 4;              // 0..15
                const int cl = (t & 15) * 4;        // 4-float sub-chunk
                const int gidx = (r < 8) ? (ta * 8 + r) : (tb * 8 + (r - 8));
                const int row  = (gidx < n) ? (int)slist[gidx] : 0;
                const float* srcf = y + (size_t)row * D;
                float* dstf = &tile[r * TS];
#pragma unroll
                for (int q = 0; q < 8; ++q) {
                    const int off = cl + q * 64;
                    *(float4*)&dstf[off] = *(const float4*)&srcf[off];
                }
            }
            __syncthreads();

            // lane owns pair (di, dj); this wave covers dims [wave*128, +128)
            {
                const float* pa = &tile[di * TS]       + wave * 128;
                const float* pb = &tile[(8 + dj) * TS] + wave * 128;
                float s0 = 0.f, s1 = 0.f, s2 = 0.f, s3 = 0.f;
#pragma unroll
                for (int kk = 0; kk < 32; kk += 4) {
                    float4 a, b; float d;
                    a = ((const float4*)pa)[kk];     b = ((const float4*)pb)[kk];
                    d = a.x - b.x; s0 += d * d;  d = a.y - b.y; s0 += d * d;
                    d = a.z - b.z; s0 += d * d;  d = a.w - b.w; s0 += d * d;
                    a = ((const float4*)pa)[kk + 1]; b = ((const float4*)pb)[kk + 1];
                    d = a.x - b.x; s1 += d * d;  d = a.y - b.y; s1 += d * d;
                    d = a.z - b.z; s1 += d * d;  d = a.w - b.w; s1 += d * d;
                    a = ((const float4*)pa)[kk + 2]; b = ((const float4*)pb)[kk + 2];
                    d = a.x - b.x; s2 += d * d;  d = a.y - b.y; s2 += d * d;
                    d = a.z - b.z; s2 += d * d;  d = a.w - b.w; s2 += d * d;
                    a = ((const float4*)pa)[kk + 3]; b = ((const float4*)pb)[kk + 3];
                    d = a.x - b.x; s3 += d * d;  d = a.y - b.y; s3 += d * d;
                    d = a.z - b.z; s3 += d * d;  d = a.w - b.w; s3 += d * d;
                }
                partials[wave][lane] = (s0 + s1) + (s2 + s3);
            }
            __syncthreads();

            if (wave == 0) {
                const float ssd = partials[0][lane] + partials[1][lane] +
                                  partials[2][lane] + partials[3][lane];
                const int i = ta * 8 + di;
                const int j = tb * 8 + dj;
                const float dd = (i < j && j < n) ? sqrtf(ssd) : -INFINITY;
                if (dd > t0) { t1 = t0; t0 = dd; }
                else if (dd > t1) { t1 = dd; }
            }
            __syncthreads();
        }

        if (wave == 0) {
#pragma unroll
            for (int off = 32; off > 0; off >>= 1) {
                const float o0 = __shfl_xor(t0, off, 64);
                const float o1 = __shfl_xor(t1, off, 64);
                if (o0 > t0) { t1 = fmaxf(t0, o1); t0 = o0; }
                else         { t1 = fmaxf(t1, o0); }
            }
            if (lane == 0) {
                blk_top[(c * G + (by - 1)) * 2]     = t0;
                blk_top[(c * G + (by - 1)) * 2 + 1] = t1;
            }
        }
    }

    // ---- completion protocol: last-arriving block computes the scalar -----
    __syncthreads();
    __threadfence();
    if (t == 0) {
        const int old = atomicAdd(cnt, 1);
        isLast = (old == TOTAL_BLOCKS - 1) ? 1 : 0;
    }
    __syncthreads();
    if (!isLast) return;
    __threadfence();  // acquire all other blocks' results

    // tail A: per-class top-2 merge (wave w -> classes 8w..8w+7)
#pragma unroll
    for (int k = 0; k < 8; ++k) {
        const int cc = wave * 8 + k;
        float t0 = blk_top[cc * G * 2 + lane];   // 64 partials on 64 lanes
        float t1 = -INFINITY;
#pragma unroll
        for (int off = 32; off > 0; off >>= 1) {
            const float o0 = __shfl_xor(t0, off, 64);
            const float o1 = __shfl_xor(t1, off, 64);
            if (o0 > t0) { t1 = fmaxf(t0, o1); t0 = o0; }
            else         { t1 = fmaxf(t1, o0); }
        }
        if (lane == 0) li_sh[cc] = 2.0f / (t0 + t1);
    }

    // tail B: center-min, LANE-per-pair (496 pairs over 256 threads)
    float dmin = INFINITY;
    for (int p = t; p < NPAIRS; p += 256) {
        int rem = p, i = 0;
        while (rem >= NC - 1 - i) { rem -= NC - 1 - i; ++i; }
        const int j = i + 1 + rem;
        const float4* ca = (const float4*)(centers + i * D);
        const float4* cb = (const float4*)(centers + j * D);
        float s0 = 0.f, s1 = 0.f, s2 = 0.f, s3 = 0.f;
#pragma unroll 4
        for (int k = 0; k < D / 4; k += 4) {
            float4 a, b; float d;
            a = ca[k];     b = cb[k];
            d = a.x - b.x; s0 += d * d;  d = a.y - b.y; s0 += d * d;
            d = a.z - b.z; s0 += d * d;  d = a.w - b.w; s0 += d * d;
            a = ca[k + 1]; b = cb[k + 1];
            d = a.x - b.x; s1 += d * d;  d = a.y - b.y; s1 += d * d;
            d = a.z - b.z; s1 += d * d;  d = a.w - b.w; s1 += d * d;
            a = ca[k + 2]; b = cb[k + 2];
            d = a.x - b.x; s2 += d * d;  d = a.y - b.y; s2 += d * d;
            d = a.z - b.z; s2 += d * d;  d = a.w - b.w; s2 += d * d;
            a = ca[k + 3]; b = cb[k + 3];
            d = a.x - b.x; s3 += d * d;  d = a.y - b.y; s3 += d * d;
            d = a.z - b.z; s3 += d * d;  d = a.w - b.w; s3 += d * d;
        }
        dmin = fminf(dmin, sqrtf((s0 + s1) + (s2 + s3)));
    }
#pragma unroll
    for (int off = 32; off > 0; off >>= 1)
        dmin = fminf(dmin, __shfl_xor(dmin, off, 64));
    if (lane == 0) mn_sh[wave] = dmin;
    __syncthreads();

    // tail C: combine
    if (t == 0) {
        float m = INFINITY;
        for (int w = 0; w < 4; ++w) m = fminf(m, mn_sh[w]);
        float s = 0.f;
        for (int cc = 0; cc < NC; ++cc) s += li_sh[cc];
        out[0] = 1.0f * s + 0.5f * fmaxf(10.0f - m, 0.0f);
    }
}

extern "C" void kernel_launch(void* const* d_in, const int* in_sizes, int n_in,
                              void* d_out, int out_size, void* d_ws, size_t ws_size,
                              hipStream_t stream) {
    const float* y      = (const float*)d_in[0];
    const int*   target = (const int*)d_in[1];
    float*       out    = (float*)d_out;

    float* centers = (float*)d_ws;
    float* blk_top = centers + NC * D;
    int*   cnt     = (int*)(blk_top + NC * G * 2);

    hipMemsetAsync(cnt, 0, sizeof(int), stream);  // reset finish counter
    fused_kernel<<<dim3(NC, G + 1), 256, 0, stream>>>(y, target, centers,
                                                      blk_top, cnt, out);
}

// Round 11
// 19.651 us; speedup vs baseline: 8.3619x; 6.3371x over previous
//
#include <hip/hip_runtime.h>
#include <math.h>

#define B 2048
#define D 512
#define NC 32
#define G  31                    // top2 subtile-blocks per class -> 32*(G+1)=1024 blocks
#define TS 516                   // LDS tile row stride in floats (512 + 4 pad)
#define NPAIRS (NC * (NC - 1) / 2)   // 496 center pairs
#define MIN_BLOCKS 124           // 124 blocks x 4 waves = 496 pair slots
#define K2_BLOCKS (MIN_BLOCKS + NC)

// ---------------------------------------------------------------------------
// Workspace: float centers[NC][D]; float blk_top[NC][G][2];
//            float cmin[MIN_BLOCKS]; float li[NC]
// 3 kernels, no fences/atomics: kernel boundaries provide cross-XCD coherence
// far cheaper than per-block __threadfence (R10 lesson: 1056 fences ~ 100us).
// ---------------------------------------------------------------------------

// Build class-c member list (ascending order) in LDS via wave shuffle-scan.
__device__ inline int build_slist(const int* __restrict__ target, int c,
                                  short* slist, int* wtot) {
    const int t = threadIdx.x;
    const int wave = t >> 6;
    const int lane = t & 63;
    const int base = t * 8;
    int flags[8];
    int local = 0;
#pragma unroll
    for (int k = 0; k < 8; ++k) {
        flags[k] = (target[base + k] == c) ? 1 : 0;
        local += flags[k];
    }
    int incl = local;
#pragma unroll
    for (int off = 1; off < 64; off <<= 1) {
        const int v = __shfl_up(incl, off, 64);
        if (lane >= off) incl += v;
    }
    if (lane == 63) wtot[wave] = incl;
    __syncthreads();
    int wbase = 0;
    for (int w = 0; w < wave; ++w) wbase += wtot[w];
    const int n = wtot[0] + wtot[1] + wtot[2] + wtot[3];
    int pos = wbase + incl - local;
#pragma unroll
    for (int k = 0; k < 8; ++k) {
        if (flags[k]) slist[pos++] = (short)(base + k);
    }
    __syncthreads();
    return n;
}

// ---------------- K1: centers + top2 partials (no protocol) ----------------

__global__ void __launch_bounds__(256)
k1_kernel(const float* __restrict__ y,
          const int* __restrict__ target,
          float* __restrict__ centers,
          float* __restrict__ blk_top) {
    const int c = blockIdx.x;
    const int by = blockIdx.y;
    const int t = threadIdx.x;
    const int wave = t >> 6;
    const int lane = t & 63;

    __shared__ short slist[B];
    __shared__ int wtot[4];
    const int n = build_slist(target, c, slist, wtot);

    if (by == 0) {
        // -------- centers role: thread owns dims t, t+256; 8-way unrolled --
        float acc0 = 0.f, acc1 = 0.f;
        int m = 0;
        for (; m + 8 <= n; m += 8) {
#pragma unroll
            for (int k = 0; k < 8; ++k) {
                const float* r = y + (size_t)slist[m + k] * D;
                acc0 += r[t];
                acc1 += r[t + 256];
            }
        }
        for (; m < n; ++m) {
            const float* r = y + (size_t)slist[m] * D;
            acc0 += r[t];
            acc1 += r[t + 256];
        }
        const float den = fmaxf((float)n, 1.0f);
        centers[c * D + t]       = acc0 / den;
        centers[c * D + t + 256] = acc1 / den;
        return;
    }

    // -------- top2 role: 8x8 pair subtiles staged through LDS --------------
    __shared__ float tile[16 * TS];
    __shared__ float partials[4][64];
    const int nt = (n + 7) >> 3;
    const int nst = nt * (nt + 1) / 2;
    const int di = lane >> 3;
    const int dj = lane & 7;
    float t0 = -INFINITY, t1 = -INFINITY;  // wave-0 running top2

    for (int st = by - 1; st < nst; st += G) {
        int rem = st, ta = 0;
        while (rem >= nt - ta) { rem -= nt - ta; ++ta; }
        const int tb = ta + rem;

        // stage 16 rows; column-interleaved -> conflict-free ds_write_b128
        {
            const int r  = t >> 4;              // 0..15
            const int cl = (t & 15) * 4;        // 4-float sub-chunk
            const int gidx = (r < 8) ? (ta * 8 + r) : (tb * 8 + (r - 8));
            const int row  = (gidx < n) ? (int)slist[gidx] : 0;
            const float* srcf = y + (size_t)row * D;
            float* dstf = &tile[r * TS];
#pragma unroll
            for (int q = 0; q < 8; ++q) {
                const int off = cl + q * 64;
                *(float4*)&dstf[off] = *(const float4*)&srcf[off];
            }
        }
        __syncthreads();

        // lane owns pair (di, dj); this wave covers dims [wave*128, +128)
        {
            const float* pa = &tile[di * TS]       + wave * 128;
            const float* pb = &tile[(8 + dj) * TS] + wave * 128;
            float s0 = 0.f, s1 = 0.f, s2 = 0.f, s3 = 0.f;
#pragma unroll
            for (int kk = 0; kk < 32; kk += 4) {
                float4 a, b; float d;
                a = ((const float4*)pa)[kk];     b = ((const float4*)pb)[kk];
                d = a.x - b.x; s0 += d * d;  d = a.y - b.y; s0 += d * d;
                d = a.z - b.z; s0 += d * d;  d = a.w - b.w; s0 += d * d;
                a = ((const float4*)pa)[kk + 1]; b = ((const float4*)pb)[kk + 1];
                d = a.x - b.x; s1 += d * d;  d = a.y - b.y; s1 += d * d;
                d = a.z - b.z; s1 += d * d;  d = a.w - b.w; s1 += d * d;
                a = ((const float4*)pa)[kk + 2]; b = ((const float4*)pb)[kk + 2];
                d = a.x - b.x; s2 += d * d;  d = a.y - b.y; s2 += d * d;
                d = a.z - b.z; s2 += d * d;  d = a.w - b.w; s2 += d * d;
                a = ((const float4*)pa)[kk + 3]; b = ((const float4*)pb)[kk + 3];
                d = a.x - b.x; s3 += d * d;  d = a.y - b.y; s3 += d * d;
                d = a.z - b.z; s3 += d * d;  d = a.w - b.w; s3 += d * d;
            }
            partials[wave][lane] = (s0 + s1) + (s2 + s3);
        }
        __syncthreads();

        if (wave == 0) {
            const float ssd = partials[0][lane] + partials[1][lane] +
                              partials[2][lane] + partials[3][lane];
            const int i = ta * 8 + di;
            const int j = tb * 8 + dj;
            const float dd = (i < j && j < n) ? sqrtf(ssd) : -INFINITY;
            if (dd > t0) { t1 = t0; t0 = dd; }
            else if (dd > t1) { t1 = dd; }
        }
        __syncthreads();
    }

    if (wave == 0) {
#pragma unroll
        for (int off = 32; off > 0; off >>= 1) {
            const float o0 = __shfl_xor(t0, off, 64);
            const float o1 = __shfl_xor(t1, off, 64);
            if (o0 > t0) { t1 = fmaxf(t0, o1); t0 = o0; }
            else         { t1 = fmaxf(t1, o0); }
        }
        if (lane == 0) {
            blk_top[(c * G + (by - 1)) * 2]     = t0;
            blk_top[(c * G + (by - 1)) * 2 + 1] = t1;
        }
    }
}

// ---------------- K2: center-min (wave-per-pair) + class top2 merge --------

__global__ void __launch_bounds__(256)
k2_kernel(const float* __restrict__ centers,
          const float* __restrict__ blk_top,
          float* __restrict__ cmin,
          float* __restrict__ li) {
    const int bid = blockIdx.x;
    const int t = threadIdx.x;
    const int wave = t >> 6;
    const int lane = t & 63;

    if (bid < MIN_BLOCKS) {
        // ---- one of 496 pairs per wave, lanes split D ----
        __shared__ float sm[4];
        const int p = bid * 4 + wave;    // 0..495, exact triangular decode
        int rem = p, i = 0;
        while (rem >= NC - 1 - i) { rem -= NC - 1 - i; ++i; }
        const int j = i + 1 + rem;
        const float4* ca = (const float4*)(centers + i * D) + lane * 2;
        const float4* cb = (const float4*)(centers + j * D) + lane * 2;
        const float4 u0 = ca[0], u1 = ca[1];
        const float4 v0 = cb[0], v1 = cb[1];
        float d, ssd = 0.f;
        d = u0.x - v0.x; ssd += d * d;
        d = u0.y - v0.y; ssd += d * d;
        d = u0.z - v0.z; ssd += d * d;
        d = u0.w - v0.w; ssd += d * d;
        d = u1.x - v1.x; ssd += d * d;
        d = u1.y - v1.y; ssd += d * d;
        d = u1.z - v1.z; ssd += d * d;
        d = u1.w - v1.w; ssd += d * d;
#pragma unroll
        for (int off = 32; off > 0; off >>= 1) ssd += __shfl_xor(ssd, off, 64);
        if (lane == 0) sm[wave] = sqrtf(ssd);
        __syncthreads();
        if (t == 0) {
            float m = INFINITY;
            for (int w = 0; w < 4; ++w) m = fminf(m, sm[w]);
            cmin[bid] = m;
        }
    } else if (wave == 0) {
        // ---- per-class top-2 merge: 2*G = 62 partials on 64 lanes ----
        const int c = bid - MIN_BLOCKS;
        float t0 = (lane < 2 * G) ? blk_top[c * G * 2 + lane] : -INFINITY;
        float t1 = -INFINITY;
#pragma unroll
        for (int off = 32; off > 0; off >>= 1) {
            const float o0 = __shfl_xor(t0, off, 64);
            const float o1 = __shfl_xor(t1, off, 64);
            if (o0 > t0) { t1 = fmaxf(t0, o1); t0 = o0; }
            else         { t1 = fmaxf(t1, o0); }
        }
        if (lane == 0) li[c] = 2.0f / (t0 + t1);
    }
}

// ---------------- K3: tiny final combine -----------------------------------

__global__ void __launch_bounds__(256)
k3_kernel(const float* __restrict__ cmin,
          const float* __restrict__ li,
          float* __restrict__ out) {
    const int t = threadIdx.x;
    const int wave = t >> 6;
    const int lane = t & 63;
    __shared__ float mn_sh[4];
    __shared__ float li_sh[1];

    float v = (t < MIN_BLOCKS) ? cmin[t] : INFINITY;
#pragma unroll
    for (int off = 32; off > 0; off >>= 1) v = fminf(v, __shfl_xor(v, off, 64));
    if (lane == 0) mn_sh[wave] = v;

    if (wave == 1) {  // parallel: sum li on wave 1
        float s = (lane < NC) ? li[lane] : 0.f;
#pragma unroll
        for (int off = 32; off > 0; off >>= 1) s += __shfl_xor(s, off, 64);
        if (lane == 0) li_sh[0] = s;
    }
    __syncthreads();
    if (t == 0) {
        float m = INFINITY;
        for (int w = 0; w < 4; ++w) m = fminf(m, mn_sh[w]);
        out[0] = 1.0f * li_sh[0] + 0.5f * fmaxf(10.0f - m, 0.0f);
    }
}

extern "C" void kernel_launch(void* const* d_in, const int* in_sizes, int n_in,
                              void* d_out, int out_size, void* d_ws, size_t ws_size,
                              hipStream_t stream) {
    const float* y      = (const float*)d_in[0];
    const int*   target = (const int*)d_in[1];
    float*       out    = (float*)d_out;

    float* centers = (float*)d_ws;
    float* blk_top = centers + NC * D;
    float* cmin    = blk_top + NC * G * 2;
    float* li      = cmin + MIN_BLOCKS;

    k1_kernel<<<dim3(NC, G + 1), 256, 0, stream>>>(y, target, centers, blk_top);
    k2_kernel<<<K2_BLOCKS, 256, 0, stream>>>(centers, blk_top, cmin, li);
    k3_kernel<<<1, 256, 0, stream>>>(cmin, li, out);
}